// Round 15
// baseline (251.299 us; speedup 1.0000x reference)
//
#include <hip/hip_runtime.h>
#include <hip/hip_cooperative_groups.h>
#include <hip/hip_fp16.h>
#include <math.h>

namespace cg = cooperative_groups;

#define BB 8
#define NPTS 524288
#define G 128
#define GG (G*G)
#define SWORDS 40960      // u32 words per stage block: pv 16384 + tv 16384 + cn 8192

// ws layout in floats
#define OFF_FIELD 0
#define OFF_COUNT (BB*4*GG)              // 524288
#define OFF_FAMAX (OFF_COUNT + BB*GG)    // 655360 (8 u32 famax)
#define OFF_FLAG  (OFF_FAMAX + 8)        // 655368 (8 u32 per-batch hole flags)
#define OFF_T     (OFF_FAMAX + 24)       // 655384 (16B aligned)
#define OFF_Y     (OFF_T + BB*2*GG*2)
#define OFF_STAGE (OFF_T)                // stage aliases T/Y (dead before DFT)

__device__ __forceinline__ unsigned pack_h2(float x, float y) {
    __half2 h = __floats2half2_rn(x, y);
    return *(unsigned*)&h;
}

// ================= MEGA: whole pipeline, one cooperative kernel ==============
// 256 blocks x 1024 thr x 160KB LDS = 1 block/CU, co-resident.
// phase 1 scatter  = R9's counting-sort body verbatim (best measured: 53us)
// phase 2 reduce   = 16-wave coalesced remap, rep split in quarters + LDS join
// phase 3 holefill = flag-guarded (blocks 0..31)
// phase 4 dft0, phase 5 dft1(+famax), phase 6 loss (blocks 0..7)
// Eliminates 5 kernel-launch gaps (~19us measured at R9).
__global__ __launch_bounds__(1024) void k_mega(const float4* __restrict__ co4,
                                               const float4* __restrict__ yp4,
                                               const float4* __restrict__ yt4,
                                               unsigned* __restrict__ stage,
                                               float* __restrict__ field,
                                               float* __restrict__ cnt,
                                               unsigned* __restrict__ famax,
                                               unsigned* __restrict__ flags,
                                               float* __restrict__ T,
                                               float* __restrict__ Y,
                                               float* __restrict__ out) {
    cg::grid_group grid = cg::this_grid();
    extern __shared__ unsigned sm[];                       // [40960] = 160KB
    const int t = threadIdx.x;
    const int blk = blockIdx.x;

    // ---- init (block 0) ----
    if (blk == 0) {
        if (t < 8) famax[t] = 0u;
        if (t >= 8 && t < 16) flags[t - 8] = 0u;
        if (t == 16) out[0] = 0.f;
    }

    // =================== phase 1: scatter (R9 body) =========================
    {
        unsigned* c16 = sm;                                // 8192 u32 = 16384 u16
        unsigned long long* data = (unsigned long long*)(sm + 8192);
        unsigned* dscr = sm + 8192;                        // scan scratch (data dead)
        const unsigned qbase = (unsigned)blk * 4096u;

        for (int k = t; k < 8192; k += 1024) c16[k] = 0u;
        __syncthreads();

        unsigned cr[16];                                   // cell | rank<<16
#pragma unroll
        for (int g = 0; g < 4; g++) {
            unsigned qa = qbase + (unsigned)(g * 1024 + t);
            float4 A = co4[3u * qa], B = co4[3u * qa + 1], C = co4[3u * qa + 2];
            float cx[4], cy[4];
            cx[0] = A.x; cy[0] = A.y; cx[1] = A.w; cy[1] = B.x;
            cx[2] = B.z; cy[2] = B.w; cx[3] = C.y; cy[3] = C.z;
#pragma unroll
            for (int j = 0; j < 4; j++) {
                // exactly mirror reference arithmetic (div then mul)
                float xn = (cx[j] - 0.0f) / 4.5f * 127.0f;
                float yn = (cy[j] - 0.5f) / 5.0f * 127.0f;
                int xi = min(max((int)rintf(xn), 0), G - 1);
                int yi = min(max((int)rintf(yn), 0), G - 1);
                unsigned cell = (unsigned)(yi * G + xi);
                unsigned sh = (cell & 1u) * 16u;
                unsigned old = atomicAdd(&c16[cell >> 1], 1u << sh);
                unsigned rank = (old >> sh) & 0xFFFFu;
                cr[g * 4 + j] = cell | (rank << 16);
            }
        }
        __syncthreads();

        // exclusive prefix scan of 16384 u16 counts -> offsets
        unsigned w[8], ssum = 0;
#pragma unroll
        for (int j = 0; j < 8; j++) {
            w[j] = c16[8 * t + j];
            ssum += (w[j] & 0xFFFFu) + (w[j] >> 16);
        }
        unsigned lane = (unsigned)t & 63u, wid = (unsigned)t >> 6;
        unsigned inc = ssum;
        for (int off = 1; off < 64; off <<= 1) {
            unsigned v = __shfl_up(inc, off);
            if (lane >= (unsigned)off) inc += v;
        }
        if (lane == 63u) dscr[wid] = inc;                  // 16 wave totals
        __syncthreads();
        unsigned wbase = 0;
#pragma unroll
        for (int k = 0; k < 16; k++) {
            unsigned v = dscr[k];
            if ((unsigned)k < wid) wbase += v;
        }
        unsigned ex = wbase + inc - ssum;
#pragma unroll
        for (int j = 0; j < 8; j++) {
            unsigned c0 = w[j] & 0xFFFFu, c1 = w[j] >> 16;
            c16[8 * t + j] = ex | ((ex + c0) << 16);       // offsets (u16 pair)
            ex += c0 + c1;
        }
        __syncthreads();

        // pass B: load values (strided), place sorted (non-atomic ds_write)
        const unsigned short* off16 = (const unsigned short*)c16;
#pragma unroll
        for (int g = 0; g < 4; g++) {
            unsigned qa = qbase + (unsigned)(g * 1024 + t);
            float4 P0 = yp4[2u * qa], P1 = yp4[2u * qa + 1];
            float4 Q0 = yt4[2u * qa], Q1 = yt4[2u * qa + 1];
            unsigned pv[4], tv[4];
            pv[0] = pack_h2(P0.x, P0.y); pv[1] = pack_h2(P0.z, P0.w);
            pv[2] = pack_h2(P1.x, P1.y); pv[3] = pack_h2(P1.z, P1.w);
            tv[0] = pack_h2(Q0.x, Q0.y); tv[1] = pack_h2(Q0.z, Q0.w);
            tv[2] = pack_h2(Q1.x, Q1.y); tv[3] = pack_h2(Q1.z, Q1.w);
#pragma unroll
            for (int j = 0; j < 4; j++) {
                unsigned c = cr[g * 4 + j] & 0xFFFFu;
                unsigned rank = cr[g * 4 + j] >> 16;
                unsigned pos = (unsigned)off16[c] + rank;
                data[pos] = ((unsigned long long)tv[j] << 32) | (unsigned long long)pv[j];
            }
        }
        __syncthreads();

        // pass C: per-cell f32 accumulation, pack f16, dump stage
        unsigned* sb = stage + (size_t)blk * SWORDS;
        unsigned o[17];
#pragma unroll
        for (int j = 0; j < 8; j++) {
            unsigned wv = c16[8 * t + j];
            o[2 * j] = wv & 0xFFFFu;
            o[2 * j + 1] = wv >> 16;
        }
        o[16] = (t == 1023) ? 16384u : (unsigned)off16[16 * (t + 1)];
        unsigned pvw[16], tvw[16];
#pragma unroll
        for (int k = 0; k < 16; k++) {
            float pr = 0.f, pi = 0.f, tr = 0.f, ti = 0.f;
            for (unsigned j = o[k]; j < o[k + 1]; j++) {
                unsigned long long d = data[j];
                unsigned lo = (unsigned)d, hi = (unsigned)(d >> 32);
                float2 fp = __half22float2(*(__half2*)&lo);
                float2 ft = __half22float2(*(__half2*)&hi);
                pr += fp.x; pi += fp.y; tr += ft.x; ti += ft.y;
            }
            pvw[k] = pack_h2(pr, pi);
            tvw[k] = pack_h2(tr, ti);
        }
#pragma unroll
        for (int j = 0; j < 4; j++)
            *(uint4*)(sb + 16 * t + 4 * j) = make_uint4(pvw[4*j], pvw[4*j+1], pvw[4*j+2], pvw[4*j+3]);
#pragma unroll
        for (int j = 0; j < 4; j++)
            *(uint4*)(sb + 16384 + 16 * t + 4 * j) = make_uint4(tvw[4*j], tvw[4*j+1], tvw[4*j+2], tvw[4*j+3]);
#pragma unroll
        for (int j = 0; j < 8; j++) {
            float ce = (float)(o[2 * j + 1] - o[2 * j]);
            float cd = (float)(o[2 * j + 2] - o[2 * j + 1]);
            sb[32768 + 8 * t + j] = pack_h2(ce, cd);
        }
    }
    grid.sync();

    // =================== phase 2: reduce (all 16 waves, coalesced) ==========
    {
        unsigned wave = (unsigned)t >> 6, lane = (unsigned)t & 63u;
        unsigned wave_id = (unsigned)blk * 16u + wave;
        unsigned ggrp = wave_id >> 2;              // pair-group (64 pairs)
        unsigned q = wave_id & 3u;                 // rep quarter
        unsigned lg = wave >> 2;                   // local group 0..3
        unsigned pair = ggrp * 64u + lane;         // 0..65535
        unsigned k = pair & 8191u;
        unsigned b = pair >> 13;
        const unsigned* sb = stage + (size_t)b * 32u * SWORDS;
        float p0r = 0, p0i = 0, p1r = 0, p1i = 0;
        float t0r = 0, t0i = 0, t1r = 0, t1i = 0;
        float n0 = 0, n1 = 0;
        for (unsigned r = q * 8u; r < q * 8u + 8u; r++) {
            const unsigned* pp = sb + (size_t)r * SWORDS;
            uint2 pv = *(const uint2*)(pp + 2 * k);
            uint2 tv = *(const uint2*)(pp + 16384 + 2 * k);
            unsigned cw = pp[32768 + k];
            float2 f;
            f = __half22float2(*(__half2*)&pv.x); p0r += f.x; p0i += f.y;
            f = __half22float2(*(__half2*)&pv.y); p1r += f.x; p1i += f.y;
            f = __half22float2(*(__half2*)&tv.x); t0r += f.x; t0i += f.y;
            f = __half22float2(*(__half2*)&tv.y); t1r += f.x; t1i += f.y;
            f = __half22float2(*(__half2*)&cw);   n0  += f.x; n1  += f.y;
        }
        float* smf = (float*)sm;                   // 3*4*64*11*4B = 33.8KB
        if (q != 0) {
            float* dst = smf + (((q - 1u) * 4u + lg) * 64u + lane) * 11u;
            dst[0] = p0r; dst[1] = p0i; dst[2] = p1r; dst[3] = p1i;
            dst[4] = t0r; dst[5] = t0i; dst[6] = t1r; dst[7] = t1i;
            dst[8] = n0;  dst[9] = n1;
        }
        __syncthreads();
        if (q == 0) {
#pragma unroll
            for (int qq = 0; qq < 3; qq++) {
                const float* src = smf + (((unsigned)qq * 4u + lg) * 64u + lane) * 11u;
                p0r += src[0]; p0i += src[1]; p1r += src[2]; p1i += src[3];
                t0r += src[4]; t0i += src[5]; t1r += src[6]; t1i += src[7];
                n0 += src[8]; n1 += src[9];
            }
            int hole = (n0 == 0.f) || (n1 == 0.f);
            if (__any(hole)) { if (lane == 0) atomicOr(&flags[b], 1u); }
            if (n0 > 0.f) { p0r /= n0; p0i /= n0; t0r /= n0; t0i /= n0; }
            if (n1 > 0.f) { p1r /= n1; p1i /= n1; t1r /= n1; t1i /= n1; }
            float2* f2 = (float2*)field;
            size_t o = (size_t)b * 4 * (GG / 2) + k;
            f2[o]                = make_float2(p0r, p1r);
            f2[o + (GG / 2)]     = make_float2(p0i, p1i);
            f2[o + 2 * (GG / 2)] = make_float2(t0r, t1r);
            f2[o + 3 * (GG / 2)] = make_float2(t0i, t1i);
            ((float2*)cnt)[(size_t)b * (GG / 2) + k] = make_float2(n0, n1);
        }
    }
    grid.sync();

    // =================== phase 3: hole-fill (blocks 0..31, flag-guarded) ====
    {
        int hb = blk >> 2, ch = blk & 3;
        if (blk < 32 && flags[hb] != 0u) {
            float* fs = (float*)sm;          // [G*G]
            float* cs = fs + GG;             // [G*G]  (128KB total, fits)
            float* fg = field + ((size_t)hb * 4 + ch) * GG;
            const float* cg = cnt + (size_t)hb * GG;
            for (int k = 0; k < 16; k++) {
                int cell = t + k * 1024;
                cs[cell] = cg[cell];
                fs[cell] = fg[cell];
            }
            __syncthreads();
            float nf[16], nc[16];
            for (int it = 0; it < 3; ++it) {
                for (int k = 0; k < 16; k++) {
                    int cell = t + k * 1024;
                    int y = cell >> 7, x = cell & 127;
                    float c = cs[cell];
                    float f = fs[cell];
                    if (c == 0.f) {
                        float s9 = 0.f;   // field: edge-replicate pad
                        for (int dy = -1; dy <= 1; dy++)
                            for (int dx = -1; dx <= 1; dx++) {
                                int yy = min(max(y + dy, 0), G - 1);
                                int xx = min(max(x + dx, 0), G - 1);
                                s9 += fs[yy * G + xx];
                            }
                        f = s9 * (1.0f / 9.0f);
                        float c9 = 0.f;   // count: zero pad
                        for (int dy = -1; dy <= 1; dy++)
                            for (int dx = -1; dx <= 1; dx++) {
                                int yy = y + dy, xx = x + dx;
                                if (yy >= 0 && yy < G && xx >= 0 && xx < G) c9 += cs[yy * G + xx];
                            }
                        if (c9 > 0.f) c = 1.0f;
                    }
                    nf[k] = f; nc[k] = c;
                }
                __syncthreads();
                for (int k = 0; k < 16; k++) {
                    int cell = t + k * 1024;
                    fs[cell] = nf[k];
                    cs[cell] = nc[k];
                }
                __syncthreads();
            }
            for (int k = 0; k < 16; k++) {
                int cell = t + k * 1024;
                fg[cell] = fs[cell];
            }
        }
    }
    grid.sync();

    // =================== phase 4: DFT pass 0 (field -> T) ===================
    {
        float2* xs = (float2*)sm;                  // [8][128]
        int rc = blk & 15, bf = blk >> 4;
        const float* re = field + ((size_t)(bf >> 1) * 4 + (size_t)(bf & 1) * 2) * GG + rc * 8 * G;
        const float* im = re + GG;
        xs[t] = make_float2(re[t], im[t]);
        __syncthreads();
        if (t < 512) {
            int rloc = t >> 6;                     // 0..7
            int kk = t & 63;
            float ang = -3.14159265358979323846f / 64.0f * (float)kk;
            float si, sr;
            sincosf(ang, &si, &sr);
            float er = 0.f, ei = 0.f, odr = 0.f, odi = 0.f;
            float tr = 1.f, ti = 0.f;
#pragma unroll 8
            for (int n = 0; n < 128; n += 2) {
                float2 x0 = xs[rloc * 128 + n];
                er += x0.x * tr - x0.y * ti;  ei += x0.x * ti + x0.y * tr;
                float t2r = tr * sr - ti * si, t2i = tr * si + ti * sr;
                float2 x1 = xs[rloc * 128 + n + 1];
                odr += x1.x * t2r - x1.y * t2i;  odi += x1.x * t2i + x1.y * t2r;
                tr = t2r * sr - t2i * si;  ti = t2r * si + t2i * sr;
            }
            float2* ob = (float2*)T + (size_t)bf * GG;
            int r0 = rc * 8 + rloc;
            ob[kk * G + r0]        = make_float2(er + odr, ei + odi);
            ob[(kk + 64) * G + r0] = make_float2(er - odr, ei - odi);
        }
    }
    grid.sync();

    // =================== phase 5: DFT pass 1 (T -> Y, famax) ================
    {
        float2* xs = (float2*)sm;
        int rc = blk & 15, bf = blk >> 4;
        const float2* cx = (const float2*)T + (size_t)bf * GG + rc * 8 * G;
        xs[t] = cx[t];
        __syncthreads();
        if (t < 512) {
            int rloc = t >> 6;
            int kk = t & 63;
            float ang = -3.14159265358979323846f / 64.0f * (float)kk;
            float si, sr;
            sincosf(ang, &si, &sr);
            float er = 0.f, ei = 0.f, odr = 0.f, odi = 0.f;
            float tr = 1.f, ti = 0.f;
#pragma unroll 8
            for (int n = 0; n < 128; n += 2) {
                float2 x0 = xs[rloc * 128 + n];
                er += x0.x * tr - x0.y * ti;  ei += x0.x * ti + x0.y * tr;
                float t2r = tr * sr - ti * si, t2i = tr * si + ti * sr;
                float2 x1 = xs[rloc * 128 + n + 1];
                odr += x1.x * t2r - x1.y * t2i;  odi += x1.x * t2i + x1.y * t2r;
                tr = t2r * sr - t2i * si;  ti = t2r * si + t2i * sr;
            }
            float2 a0 = make_float2(er + odr, ei + odi);
            float2 a1 = make_float2(er - odr, ei - odi);
            float2* ob = (float2*)Y + (size_t)bf * GG;
            int r0 = rc * 8 + rloc;
            ob[kk * G + r0]        = a0;
            ob[(kk + 64) * G + r0] = a1;
            if (bf & 1) {   // fft_true: raw |Y| max per batch
                float m = fmaxf(sqrtf(a0.x * a0.x + a0.y * a0.y),
                                sqrtf(a1.x * a1.x + a1.y * a1.y));
                for (int off = 32; off; off >>= 1) m = fmaxf(m, __shfl_down(m, off));
                if ((t & 63) == 0) atomicMax(&famax[bf >> 1], __float_as_uint(m));
            }
        }
    }
    grid.sync();

    // =================== phase 6: loss (blocks 0..7) ========================
    if (blk < 8) {
        int b = blk;
        const float2* Yp = (const float2*)Y + (size_t)(b * 2 + 0) * GG;
        const float2* Yt = (const float2*)Y + (size_t)(b * 2 + 1) * GG;
        const float s = (4.5f / 127.0f) * (5.0f / 127.0f);   // dx*dy
        float fam = __uint_as_float(famax[b]) * s;
        float fam2 = fam * fam + 1e-10f;
        float thr = fam / 1000.0f;
        float swd = 0.f, smask = 0.f;
        for (int k = 0; k < 16; k++) {
            int idx = t + k * 1024;
            float2 p = Yp[idx], tt = Yt[idx];
            float pr = p.x * s, pi = p.y * s;
            float qr = tt.x * s, qi = tt.y * s;
            float fa = sqrtf(qr * qr + qi * qi);
            if (fa >= thr) {
                float w = fa * fa / fam2;
                float dr = pr - qr, di = pi - qi;
                swd += (dr * dr + di * di) * w;
                smask += 1.f;
            }
        }
        for (int off = 32; off; off >>= 1) {
            swd += __shfl_down(swd, off);
            smask += __shfl_down(smask, off);
        }
        float* rs = (float*)sm;
        float* rm = rs + 16;
        int wid = t >> 6, lane = t & 63;
        if (lane == 0) { rs[wid] = swd; rm[wid] = smask; }
        __syncthreads();
        if (t == 0) {
            float a = 0.f, m = 0.f;
            for (int w = 0; w < 16; w++) { a += rs[w]; m += rm[w]; }
            atomicAdd(out, (a / (m + 1e-10f)) * 0.125f);
        }
    }
}

// ======== fallback path (ws too small for rep=32 stage): separate kernels ===
__global__ __launch_bounds__(1024) void k_scatter(const float4* __restrict__ co4,
                                                  const float4* __restrict__ yp4,
                                                  const float4* __restrict__ yt4,
                                                  unsigned* __restrict__ stage,
                                                  unsigned* __restrict__ flags,
                                                  int rep) {
    extern __shared__ unsigned sm[];
    int blk = blockIdx.x;
    int r = blk % rep;
    int b = blk / rep;
    if (blk == 0 && threadIdx.x < 8) flags[threadIdx.x] = 0u;
    for (int k = threadIdx.x; k < SWORDS / 4; k += 1024)
        ((uint4*)sm)[k] = make_uint4(0u, 0u, 0u, 0u);
    __syncthreads();
    unsigned ldsbase = (unsigned)(uintptr_t)sm;
    int ppb = NPTS / rep;
    int nq = ppb >> 2;
    size_t qbase = ((size_t)b * NPTS + (size_t)r * ppb) >> 2;
#define DOPT(cx, cy, vx, vy, wx, wy) do {                                   \
        float xn = ((cx) - 0.0f) / 4.5f * 127.0f;                           \
        float yn = ((cy) - 0.5f) / 5.0f * 127.0f;                           \
        int xi = min(max((int)rintf(xn), 0), G - 1);                        \
        int yi = min(max((int)rintf(yn), 0), G - 1);                        \
        unsigned cell = (unsigned)(yi * G + xi);                            \
        unsigned av = ldsbase + cell * 4u;                                  \
        asm volatile("ds_pk_add_f16 %0, %1" :: "v"(av), "v"(pack_h2(vx, vy))); \
        asm volatile("ds_pk_add_f16 %0, %1" :: "v"(av + 65536u), "v"(pack_h2(wx, wy))); \
        unsigned ac = ldsbase + 131072u + (cell >> 1) * 4u;                 \
        unsigned cw = (cell & 1u) ? 0x3C000000u : 0x00003C00u;              \
        asm volatile("ds_pk_add_f16 %0, %1" :: "v"(ac), "v"(cw));           \
    } while (0)
    for (int q = threadIdx.x; q < nq; q += 2048) {
        size_t qa = qbase + q, qb = qa + 1024;
        float4 A0 = co4[3 * qa], B0 = co4[3 * qa + 1], C0 = co4[3 * qa + 2];
        float4 P00 = yp4[2 * qa], P01 = yp4[2 * qa + 1];
        float4 Q00 = yt4[2 * qa], Q01 = yt4[2 * qa + 1];
        float4 A1 = co4[3 * qb], B1 = co4[3 * qb + 1], C1 = co4[3 * qb + 2];
        float4 P10 = yp4[2 * qb], P11 = yp4[2 * qb + 1];
        float4 Q10 = yt4[2 * qb], Q11 = yt4[2 * qb + 1];
        DOPT(A0.x, A0.y, P00.x, P00.y, Q00.x, Q00.y);
        DOPT(A0.w, B0.x, P00.z, P00.w, Q00.z, Q00.w);
        DOPT(B0.z, B0.w, P01.x, P01.y, Q01.x, Q01.y);
        DOPT(C0.y, C0.z, P01.z, P01.w, Q01.z, Q01.w);
        DOPT(A1.x, A1.y, P10.x, P10.y, Q10.x, Q10.y);
        DOPT(A1.w, B1.x, P10.z, P10.w, Q10.z, Q10.w);
        DOPT(B1.z, B1.w, P11.x, P11.y, Q11.x, Q11.y);
        DOPT(C1.y, C1.z, P11.z, P11.w, Q11.z, Q11.w);
    }
#undef DOPT
    asm volatile("s_waitcnt lgkmcnt(0)" ::: "memory");
    __syncthreads();
    unsigned* sb = stage + (size_t)blk * SWORDS;
    for (int k = threadIdx.x * 4; k < SWORDS; k += 4096)
        *(uint4*)(sb + k) = *(const uint4*)(sm + k);
}

__global__ __launch_bounds__(256) void k_reduce(const unsigned* __restrict__ stage,
                                                float* __restrict__ field,
                                                float* __restrict__ cnt,
                                                unsigned* __restrict__ famax,
                                                unsigned* __restrict__ flags,
                                                float* __restrict__ out,
                                                int rep) {
    if (blockIdx.x == 0) {
        if (threadIdx.x < 8) famax[threadIdx.x] = 0u;
        if (threadIdx.x == 8) out[0] = 0.f;
    }
    int idx = blockIdx.x * 256 + threadIdx.x;
    int k = idx & 8191;
    int b = idx >> 13;
    const unsigned* sb = stage + (size_t)b * rep * SWORDS;
    float p0r = 0, p0i = 0, p1r = 0, p1i = 0;
    float t0r = 0, t0i = 0, t1r = 0, t1i = 0;
    float n0 = 0, n1 = 0;
    for (int r = 0; r < rep; r++) {
        const unsigned* pp = sb + (size_t)r * SWORDS;
        uint2 pv = *(const uint2*)(pp + 2 * k);
        uint2 tv = *(const uint2*)(pp + 16384 + 2 * k);
        unsigned cw = pp[32768 + k];
        float2 f;
        f = __half22float2(*(__half2*)&pv.x); p0r += f.x; p0i += f.y;
        f = __half22float2(*(__half2*)&pv.y); p1r += f.x; p1i += f.y;
        f = __half22float2(*(__half2*)&tv.x); t0r += f.x; t0i += f.y;
        f = __half22float2(*(__half2*)&tv.y); t1r += f.x; t1i += f.y;
        f = __half22float2(*(__half2*)&cw);   n0  += f.x; n1  += f.y;
    }
    int hole = (n0 == 0.f) || (n1 == 0.f);
    if (__any(hole)) {
        if ((threadIdx.x & 63) == 0) atomicOr(&flags[b], 1u);
    }
    if (n0 > 0.f) { p0r /= n0; p0i /= n0; t0r /= n0; t0i /= n0; }
    if (n1 > 0.f) { p1r /= n1; p1i /= n1; t1r /= n1; t1i /= n1; }
    float2* f2 = (float2*)field;
    size_t o = (size_t)b * 4 * (GG / 2) + k;
    f2[o]                = make_float2(p0r, p1r);
    f2[o + (GG / 2)]     = make_float2(p0i, p1i);
    f2[o + 2 * (GG / 2)] = make_float2(t0r, t1r);
    f2[o + 3 * (GG / 2)] = make_float2(t0i, t1i);
    ((float2*)cnt)[(size_t)b * (GG / 2) + k] = make_float2(n0, n1);
}

__global__ __launch_bounds__(1024) void k_holefill(float* __restrict__ field,
                                                   const float* __restrict__ cnt,
                                                   const unsigned* __restrict__ flags) {
    int b = blockIdx.x >> 2, ch = blockIdx.x & 3;
    if (flags[b] == 0u) return;
    extern __shared__ float smf[];
    float* fs = smf;
    float* cs = smf + GG;
    float* fg = field + ((size_t)b * 4 + ch) * GG;
    const float* cg = cnt + (size_t)b * GG;
    int tid = threadIdx.x;
    for (int k = 0; k < 16; k++) {
        int cell = tid + k * 1024;
        cs[cell] = cg[cell];
        fs[cell] = fg[cell];
    }
    __syncthreads();
    float nf[16], nc[16];
    for (int it = 0; it < 3; ++it) {
        for (int k = 0; k < 16; k++) {
            int cell = tid + k * 1024;
            int y = cell >> 7, x = cell & 127;
            float c = cs[cell];
            float f = fs[cell];
            if (c == 0.f) {
                float s9 = 0.f;
                for (int dy = -1; dy <= 1; dy++)
                    for (int dx = -1; dx <= 1; dx++) {
                        int yy = min(max(y + dy, 0), G - 1);
                        int xx = min(max(x + dx, 0), G - 1);
                        s9 += fs[yy * G + xx];
                    }
                f = s9 * (1.0f / 9.0f);
                float c9 = 0.f;
                for (int dy = -1; dy <= 1; dy++)
                    for (int dx = -1; dx <= 1; dx++) {
                        int yy = y + dy, xx = x + dx;
                        if (yy >= 0 && yy < G && xx >= 0 && xx < G) c9 += cs[yy * G + xx];
                    }
                if (c9 > 0.f) c = 1.0f;
            }
            nf[k] = f; nc[k] = c;
        }
        __syncthreads();
        for (int k = 0; k < 16; k++) {
            int cell = tid + k * 1024;
            fs[cell] = nf[k];
            cs[cell] = nc[k];
        }
        __syncthreads();
    }
    for (int k = 0; k < 16; k++) {
        int cell = tid + k * 1024;
        fg[cell] = fs[cell];
    }
}

template <int PASS>
__global__ __launch_bounds__(256) void k_dft(const float* __restrict__ in,
                                             float* __restrict__ out,
                                             unsigned* __restrict__ famax) {
    __shared__ float2 xs[8][128];
    int blk = blockIdx.x;
    int rc = blk & 15;
    int bf = blk >> 4;
    int tid = threadIdx.x;
    if (PASS == 0) {
        const float* re = in + ((size_t)(bf >> 1) * 4 + (size_t)(bf & 1) * 2) * GG + rc * 8 * G;
        const float* im = re + GG;
        for (int e = 0; e < 4; e++) {
            int idx = tid + e * 256;
            xs[idx >> 7][idx & 127] = make_float2(re[idx], im[idx]);
        }
    } else {
        const float2* cx = (const float2*)in + (size_t)bf * GG + rc * 8 * G;
        for (int e = 0; e < 4; e++) {
            int idx = tid + e * 256;
            xs[idx >> 7][idx & 127] = cx[idx];
        }
    }
    __syncthreads();

    int rloc = (tid >> 6) * 2;
    int kk = tid & 63;
    float ang = -3.14159265358979323846f / 64.0f * (float)kk;
    float si, sr;
    sincosf(ang, &si, &sr);

    float e0r = 0.f, e0i = 0.f, o0r = 0.f, o0i = 0.f;
    float e1r = 0.f, e1i = 0.f, o1r = 0.f, o1i = 0.f;
    float tr = 1.f, ti = 0.f;
#pragma unroll 8
    for (int n = 0; n < 128; n += 2) {
        float2 x0 = xs[rloc][n];
        float2 x1 = xs[rloc + 1][n];
        e0r += x0.x * tr - x0.y * ti;  e0i += x0.x * ti + x0.y * tr;
        e1r += x1.x * tr - x1.y * ti;  e1i += x1.x * ti + x1.y * tr;
        float t2r = tr * sr - ti * si, t2i = tr * si + ti * sr;
        x0 = xs[rloc][n + 1];
        x1 = xs[rloc + 1][n + 1];
        o0r += x0.x * t2r - x0.y * t2i;  o0i += x0.x * t2i + x0.y * t2r;
        o1r += x1.x * t2r - x1.y * t2i;  o1i += x1.x * t2i + x1.y * t2r;
        tr = t2r * sr - t2i * si;  ti = t2r * si + t2i * sr;
    }

    float2 a00 = make_float2(e0r + o0r, e0i + o0i);
    float2 a01 = make_float2(e1r + o1r, e1i + o1i);
    float2 a10 = make_float2(e0r - o0r, e0i - o0i);
    float2 a11 = make_float2(e1r - o1r, e1i - o1i);

    float2* ob = (float2*)out + (size_t)bf * GG;
    int r0 = rc * 8 + rloc;
    ob[kk * G + r0]            = a00;
    ob[kk * G + r0 + 1]        = a01;
    ob[(kk + 64) * G + r0]     = a10;
    ob[(kk + 64) * G + r0 + 1] = a11;

    if (PASS == 1 && (bf & 1)) {
        float m = fmaxf(fmaxf(sqrtf(a00.x * a00.x + a00.y * a00.y),
                              sqrtf(a01.x * a01.x + a01.y * a01.y)),
                        fmaxf(sqrtf(a10.x * a10.x + a10.y * a10.y),
                              sqrtf(a11.x * a11.x + a11.y * a11.y)));
        for (int off = 32; off; off >>= 1) m = fmaxf(m, __shfl_down(m, off));
        if ((tid & 63) == 0) atomicMax(&famax[bf >> 1], __float_as_uint(m));
    }
}

__global__ __launch_bounds__(1024) void k_loss(const float* __restrict__ Ybuf,
                                               const unsigned* __restrict__ famax,
                                               float* __restrict__ out) {
    int b = blockIdx.x;
    const float2* Yp = (const float2*)Ybuf + (size_t)(b * 2 + 0) * GG;
    const float2* Yt = (const float2*)Ybuf + (size_t)(b * 2 + 1) * GG;
    const float s = (4.5f / 127.0f) * (5.0f / 127.0f);
    float fam = __uint_as_float(famax[b]) * s;
    float fam2 = fam * fam + 1e-10f;
    float thr = fam / 1000.0f;
    float swd = 0.f, smask = 0.f;
    for (int k = 0; k < 16; k++) {
        int idx = threadIdx.x + k * 1024;
        float2 p = Yp[idx], t = Yt[idx];
        float pr = p.x * s, pi = p.y * s;
        float qr = t.x * s, qi = t.y * s;
        float fa = sqrtf(qr * qr + qi * qi);
        if (fa >= thr) {
            float w = fa * fa / fam2;
            float dr = pr - qr, di = pi - qi;
            swd += (dr * dr + di * di) * w;
            smask += 1.f;
        }
    }
    for (int off = 32; off; off >>= 1) {
        swd += __shfl_down(swd, off);
        smask += __shfl_down(smask, off);
    }
    __shared__ float rs[16], rm[16];
    int wid = threadIdx.x >> 6, lane = threadIdx.x & 63;
    if (lane == 0) { rs[wid] = swd; rm[wid] = smask; }
    __syncthreads();
    if (threadIdx.x == 0) {
        float a = 0.f, m = 0.f;
        for (int w = 0; w < 16; w++) { a += rs[w]; m += rm[w]; }
        atomicAdd(out, (a / (m + 1e-10f)) * 0.125f);
    }
}

extern "C" void kernel_launch(void* const* d_in, const int* in_sizes, int n_in,
                              void* d_out, int out_size, void* d_ws, size_t ws_size,
                              hipStream_t stream) {
    const float4* yp4 = (const float4*)d_in[0];
    const float4* yt4 = (const float4*)d_in[1];
    const float4* co4 = (const float4*)d_in[2];
    float* ws = (float*)d_ws;
    float* field = ws + OFF_FIELD;
    float* cnt   = ws + OFF_COUNT;
    unsigned* famax = (unsigned*)(ws + OFF_FAMAX);
    unsigned* flags = (unsigned*)(ws + OFF_FLAG);
    float* T = ws + OFF_T;
    float* Y = ws + OFF_Y;
    float* outp = (float*)d_out;
    unsigned* stage = (unsigned*)(ws + OFF_STAGE);

    int rep = 32;
    while (rep > 1 &&
           ((size_t)OFF_T + (size_t)BB * rep * SWORDS) * 4 > ws_size)
        rep >>= 1;

    if (rep == 32) {
        void* args[] = { (void*)&co4, (void*)&yp4, (void*)&yt4, (void*)&stage,
                         (void*)&field, (void*)&cnt, (void*)&famax, (void*)&flags,
                         (void*)&T, (void*)&Y, (void*)&outp };
        hipLaunchCooperativeKernel((const void*)k_mega, dim3(256), dim3(1024),
                                   args, SWORDS * sizeof(unsigned), stream);
    } else {
        k_scatter<<<BB * rep, 1024, SWORDS * sizeof(unsigned), stream>>>(
            co4, yp4, yt4, stage, flags, rep);
        k_reduce<<<BB * (GG / 2) / 256, 256, 0, stream>>>(
            stage, field, cnt, famax, flags, outp, rep);
        k_holefill<<<BB * 4, 1024, 2 * GG * sizeof(float), stream>>>(field, cnt, flags);
        k_dft<0><<<BB * 2 * 16, 256, 0, stream>>>(field, T, famax);
        k_dft<1><<<BB * 2 * 16, 256, 0, stream>>>(T, Y, famax);
        k_loss<<<BB, 1024, 0, stream>>>(Y, famax, outp);
    }
}

// Round 16
// 91.081 us; speedup vs baseline: 2.7591x; 2.7591x over previous
//
#include <hip/hip_runtime.h>
#include <hip/hip_fp16.h>
#include <math.h>

#define BB 8
#define NPTS 524288
#define G 128
#define GG (G*G)
#define SWORDS 40960      // u32 words per stage block: pv 16384 + tv 16384 + cn 8192

// ws layout in floats
#define OFF_FIELD 0
#define OFF_COUNT (BB*4*GG)              // 524288
#define OFF_FAMAX (OFF_COUNT + BB*GG)    // 655360 (8 u32 famax)
#define OFF_FLAG  (OFF_FAMAX + 8)        // 655368 (8 u32 per-batch hole flags)
#define OFF_T     (OFF_FAMAX + 24)       // 655384 (16B aligned)
#define OFF_Y     (OFF_T + BB*2*GG*2)
#define OFF_STAGE (OFF_T)                // stage aliases T/Y (dead before DFT)

__device__ __forceinline__ unsigned pack_h2(float x, float y) {
    __half2 h = __floats2half2_rn(x, y);
    return *(unsigned*)&h;
}

// ======== scatter via counting sort (R9 body, best measured: 53us) ==========
// 256 blocks x 1024 thr; 16384 pts/block. LDS: cnt16[16384] (32KB) +
// data[16384] u64 (128KB) = 160KB. 1 atomic/pt -> rank; scan -> offsets;
// pass B loads values strided and places directly to sorted positions;
// pass C accumulates per-cell in f32 and dumps the f16 stage.
__global__ __launch_bounds__(1024) void k_scatter_sort(const float4* __restrict__ co4,
                                                       const float4* __restrict__ yp4,
                                                       const float4* __restrict__ yt4,
                                                       unsigned* __restrict__ stage,
                                                       unsigned* __restrict__ flags) {
    extern __shared__ unsigned sm[];                       // [40960]
    unsigned* cnt = sm;                                    // 8192 u32 = 16384 u16
    unsigned long long* data = (unsigned long long*)(sm + 8192);   // 16384 x 8B
    unsigned* dscr = sm + 8192;                            // scan scratch (data dead)

    const int t = threadIdx.x;
    const int blk = blockIdx.x;                            // b = blk>>5, r = blk&31
    const unsigned qbase = (unsigned)blk * 4096u;          // first quad (global)

    if (blk == 0 && t < 8) flags[t] = 0u;                  // pre-zero hole flags

    for (int k = t; k < 8192; k += 1024) cnt[k] = 0u;
    __syncthreads();

    // ---- pass A: coords -> cell; atomic count gives rank (1 atomic/pt) ----
    unsigned cr[16];                                       // cell | rank<<16
#pragma unroll
    for (int g = 0; g < 4; g++) {
        unsigned qa = qbase + (unsigned)(g * 1024 + t);
        float4 A = co4[3u * qa], B = co4[3u * qa + 1], C = co4[3u * qa + 2];
        float cx[4], cy[4];
        cx[0] = A.x; cy[0] = A.y; cx[1] = A.w; cy[1] = B.x;
        cx[2] = B.z; cy[2] = B.w; cx[3] = C.y; cy[3] = C.z;
#pragma unroll
        for (int j = 0; j < 4; j++) {
            // exactly mirror reference arithmetic (div then mul)
            float xn = (cx[j] - 0.0f) / 4.5f * 127.0f;
            float yn = (cy[j] - 0.5f) / 5.0f * 127.0f;
            int xi = min(max((int)rintf(xn), 0), G - 1);
            int yi = min(max((int)rintf(yn), 0), G - 1);
            unsigned cell = (unsigned)(yi * G + xi);
            unsigned sh = (cell & 1u) * 16u;
            unsigned old = atomicAdd(&cnt[cell >> 1], 1u << sh);
            unsigned rank = (old >> sh) & 0xFFFFu;
            cr[g * 4 + j] = cell | (rank << 16);
        }
    }
    __syncthreads();

    // ---- exclusive prefix scan of 16384 u16 counts (in place -> offsets) ---
    unsigned w[8], ssum = 0;
#pragma unroll
    for (int j = 0; j < 8; j++) {
        w[j] = cnt[8 * t + j];
        ssum += (w[j] & 0xFFFFu) + (w[j] >> 16);
    }
    unsigned lane = (unsigned)t & 63u, wid = (unsigned)t >> 6;
    unsigned inc = ssum;
    for (int off = 1; off < 64; off <<= 1) {
        unsigned v = __shfl_up(inc, off);
        if (lane >= (unsigned)off) inc += v;
    }
    if (lane == 63u) dscr[wid] = inc;                      // 16 wave totals
    __syncthreads();
    unsigned wbase = 0;
#pragma unroll
    for (int k = 0; k < 16; k++) {
        unsigned v = dscr[k];
        if ((unsigned)k < wid) wbase += v;
    }
    unsigned ex = wbase + inc - ssum;                      // exclusive start
#pragma unroll
    for (int j = 0; j < 8; j++) {
        unsigned c0 = w[j] & 0xFFFFu, c1 = w[j] >> 16;
        cnt[8 * t + j] = ex | ((ex + c0) << 16);           // offsets (u16 pair)
        ex += c0 + c1;
    }
    __syncthreads();                                       // offsets final; dscr dead

    // ---- pass B: load values, place sorted (non-atomic ds_write_b64) ------
    const unsigned short* off16 = (const unsigned short*)cnt;
#pragma unroll
    for (int g = 0; g < 4; g++) {
        unsigned qa = qbase + (unsigned)(g * 1024 + t);
        float4 P0 = yp4[2u * qa], P1 = yp4[2u * qa + 1];
        float4 Q0 = yt4[2u * qa], Q1 = yt4[2u * qa + 1];
        unsigned pv[4], tv[4];
        pv[0] = pack_h2(P0.x, P0.y); pv[1] = pack_h2(P0.z, P0.w);
        pv[2] = pack_h2(P1.x, P1.y); pv[3] = pack_h2(P1.z, P1.w);
        tv[0] = pack_h2(Q0.x, Q0.y); tv[1] = pack_h2(Q0.z, Q0.w);
        tv[2] = pack_h2(Q1.x, Q1.y); tv[3] = pack_h2(Q1.z, Q1.w);
#pragma unroll
        for (int j = 0; j < 4; j++) {
            unsigned c = cr[g * 4 + j] & 0xFFFFu;
            unsigned rank = cr[g * 4 + j] >> 16;
            unsigned pos = (unsigned)off16[c] + rank;
            data[pos] = ((unsigned long long)tv[j] << 32) | (unsigned long long)pv[j];
        }
    }
    __syncthreads();

    // ---- pass C: per-cell f32 accumulation, pack f16, dump stage -----------
    unsigned* sb = stage + (size_t)blk * SWORDS;
    unsigned o[17];
#pragma unroll
    for (int j = 0; j < 8; j++) {
        unsigned wv = cnt[8 * t + j];
        o[2 * j] = wv & 0xFFFFu;
        o[2 * j + 1] = wv >> 16;
    }
    o[16] = (t == 1023) ? 16384u : (unsigned)off16[16 * (t + 1)];
    unsigned pvw[16], tvw[16];
#pragma unroll
    for (int k = 0; k < 16; k++) {
        float pr = 0.f, pi = 0.f, tr = 0.f, ti = 0.f;
        for (unsigned j = o[k]; j < o[k + 1]; j++) {
            unsigned long long d = data[j];
            unsigned lo = (unsigned)d, hi = (unsigned)(d >> 32);
            float2 fp = __half22float2(*(__half2*)&lo);
            float2 ft = __half22float2(*(__half2*)&hi);
            pr += fp.x; pi += fp.y; tr += ft.x; ti += ft.y;
        }
        pvw[k] = pack_h2(pr, pi);
        tvw[k] = pack_h2(tr, ti);
    }
#pragma unroll
    for (int j = 0; j < 4; j++)
        *(uint4*)(sb + 16 * t + 4 * j) = make_uint4(pvw[4*j], pvw[4*j+1], pvw[4*j+2], pvw[4*j+3]);
#pragma unroll
    for (int j = 0; j < 4; j++)
        *(uint4*)(sb + 16384 + 16 * t + 4 * j) = make_uint4(tvw[4*j], tvw[4*j+1], tvw[4*j+2], tvw[4*j+3]);
#pragma unroll
    for (int j = 0; j < 8; j++) {
        float ce = (float)(o[2 * j + 1] - o[2 * j]);
        float cd = (float)(o[2 * j + 2] - o[2 * j + 1]);
        sb[32768 + 8 * t + j] = pack_h2(ce, cd);
    }
}

// ======== direct scatter (fallback when ws can't hold rep=32 stage) =========
__global__ __launch_bounds__(1024) void k_scatter(const float4* __restrict__ co4,
                                                  const float4* __restrict__ yp4,
                                                  const float4* __restrict__ yt4,
                                                  unsigned* __restrict__ stage,
                                                  unsigned* __restrict__ flags,
                                                  int rep) {
    extern __shared__ unsigned sm[];   // [SWORDS]
    int blk = blockIdx.x;              // b*rep + r
    int r = blk % rep;
    int b = blk / rep;
    if (blk == 0 && threadIdx.x < 8) flags[threadIdx.x] = 0u;
    for (int k = threadIdx.x; k < SWORDS / 4; k += 1024)
        ((uint4*)sm)[k] = make_uint4(0u, 0u, 0u, 0u);
    __syncthreads();
    unsigned ldsbase = (unsigned)(uintptr_t)sm;
    int ppb = NPTS / rep;
    int nq = ppb >> 2;
    size_t qbase = ((size_t)b * NPTS + (size_t)r * ppb) >> 2;
#define DOPT(cx, cy, vx, vy, wx, wy) do {                                   \
        float xn = ((cx) - 0.0f) / 4.5f * 127.0f;                           \
        float yn = ((cy) - 0.5f) / 5.0f * 127.0f;                           \
        int xi = min(max((int)rintf(xn), 0), G - 1);                        \
        int yi = min(max((int)rintf(yn), 0), G - 1);                        \
        unsigned cell = (unsigned)(yi * G + xi);                            \
        unsigned av = ldsbase + cell * 4u;                                  \
        asm volatile("ds_pk_add_f16 %0, %1" :: "v"(av), "v"(pack_h2(vx, vy))); \
        asm volatile("ds_pk_add_f16 %0, %1" :: "v"(av + 65536u), "v"(pack_h2(wx, wy))); \
        unsigned ac = ldsbase + 131072u + (cell >> 1) * 4u;                 \
        unsigned cw = (cell & 1u) ? 0x3C000000u : 0x00003C00u;              \
        asm volatile("ds_pk_add_f16 %0, %1" :: "v"(ac), "v"(cw));           \
    } while (0)
    for (int q = threadIdx.x; q < nq; q += 2048) {
        size_t qa = qbase + q, qb = qa + 1024;
        float4 A0 = co4[3 * qa], B0 = co4[3 * qa + 1], C0 = co4[3 * qa + 2];
        float4 P00 = yp4[2 * qa], P01 = yp4[2 * qa + 1];
        float4 Q00 = yt4[2 * qa], Q01 = yt4[2 * qa + 1];
        float4 A1 = co4[3 * qb], B1 = co4[3 * qb + 1], C1 = co4[3 * qb + 2];
        float4 P10 = yp4[2 * qb], P11 = yp4[2 * qb + 1];
        float4 Q10 = yt4[2 * qb], Q11 = yt4[2 * qb + 1];
        DOPT(A0.x, A0.y, P00.x, P00.y, Q00.x, Q00.y);
        DOPT(A0.w, B0.x, P00.z, P00.w, Q00.z, Q00.w);
        DOPT(B0.z, B0.w, P01.x, P01.y, Q01.x, Q01.y);
        DOPT(C0.y, C0.z, P01.z, P01.w, Q01.z, Q01.w);
        DOPT(A1.x, A1.y, P10.x, P10.y, Q10.x, Q10.y);
        DOPT(A1.w, B1.x, P10.z, P10.w, Q10.z, Q10.w);
        DOPT(B1.z, B1.w, P11.x, P11.y, Q11.x, Q11.y);
        DOPT(C1.y, C1.z, P11.z, P11.w, Q11.z, Q11.w);
    }
#undef DOPT
    asm volatile("s_waitcnt lgkmcnt(0)" ::: "memory");
    __syncthreads();
    unsigned* sb = stage + (size_t)blk * SWORDS;
    for (int k = threadIdx.x * 4; k < SWORDS; k += 4096)
        *(uint4*)(sb + k) = *(const uint4*)(sm + k);
}

// ---- reduce replicas (f16->f32) + divide; zero famax/out; set hole flags ---
__global__ __launch_bounds__(256) void k_reduce(const unsigned* __restrict__ stage,
                                                float* __restrict__ field,
                                                float* __restrict__ cnt,
                                                unsigned* __restrict__ famax,
                                                unsigned* __restrict__ flags,
                                                float* __restrict__ out,
                                                int rep) {
    if (blockIdx.x == 0) {
        if (threadIdx.x < 8) famax[threadIdx.x] = 0u;
        if (threadIdx.x == 8) out[0] = 0.f;
    }
    int idx = blockIdx.x * 256 + threadIdx.x;    // b*8192 + k
    int k = idx & 8191;
    int b = idx >> 13;
    const unsigned* sb = stage + (size_t)b * rep * SWORDS;
    float p0r = 0, p0i = 0, p1r = 0, p1i = 0;
    float t0r = 0, t0i = 0, t1r = 0, t1i = 0;
    float n0 = 0, n1 = 0;
    for (int r = 0; r < rep; r++) {
        const unsigned* pp = sb + (size_t)r * SWORDS;
        uint2 pv = *(const uint2*)(pp + 2 * k);
        uint2 tv = *(const uint2*)(pp + 16384 + 2 * k);
        unsigned cw = pp[32768 + k];
        float2 f;
        f = __half22float2(*(__half2*)&pv.x); p0r += f.x; p0i += f.y;
        f = __half22float2(*(__half2*)&pv.y); p1r += f.x; p1i += f.y;
        f = __half22float2(*(__half2*)&tv.x); t0r += f.x; t0i += f.y;
        f = __half22float2(*(__half2*)&tv.y); t1r += f.x; t1i += f.y;
        f = __half22float2(*(__half2*)&cw);   n0  += f.x; n1  += f.y;
    }
    int hole = (n0 == 0.f) || (n1 == 0.f);
    if (__any(hole)) {
        if ((threadIdx.x & 63) == 0) atomicOr(&flags[b], 1u);
    }
    if (n0 > 0.f) { p0r /= n0; p0i /= n0; t0r /= n0; t0i /= n0; }
    if (n1 > 0.f) { p1r /= n1; p1i /= n1; t1r /= n1; t1i /= n1; }
    float2* f2 = (float2*)field;
    size_t o = (size_t)b * 4 * (GG / 2) + k;
    f2[o]                = make_float2(p0r, p1r);
    f2[o + (GG / 2)]     = make_float2(p0i, p1i);
    f2[o + 2 * (GG / 2)] = make_float2(t0r, t1r);
    f2[o + 3 * (GG / 2)] = make_float2(t0i, t1i);
    ((float2*)cnt)[(size_t)b * (GG / 2) + k] = make_float2(n0, n1);
}

// -------- hole-fill (3 iters); instant exit on per-batch flag (typical) -----
__global__ __launch_bounds__(1024) void k_holefill(float* __restrict__ field,
                                                   const float* __restrict__ cnt,
                                                   const unsigned* __restrict__ flags) {
    int b = blockIdx.x >> 2, ch = blockIdx.x & 3;
    if (flags[b] == 0u) return;      // no empty cells in this batch: done
    extern __shared__ float smf[];
    float* fs = smf;         // [G*G] field
    float* cs = smf + GG;    // [G*G] count
    float* fg = field + ((size_t)b * 4 + ch) * GG;
    const float* cg = cnt + (size_t)b * GG;
    int tid = threadIdx.x;
    for (int k = 0; k < 16; k++) {
        int cell = tid + k * 1024;
        cs[cell] = cg[cell];
        fs[cell] = fg[cell];
    }
    __syncthreads();
    float nf[16], nc[16];
    for (int it = 0; it < 3; ++it) {
        for (int k = 0; k < 16; k++) {
            int cell = tid + k * 1024;
            int y = cell >> 7, x = cell & 127;
            float c = cs[cell];
            float f = fs[cell];
            if (c == 0.f) {
                float s9 = 0.f;   // field: edge-replicate pad
                for (int dy = -1; dy <= 1; dy++)
                    for (int dx = -1; dx <= 1; dx++) {
                        int yy = min(max(y + dy, 0), G - 1);
                        int xx = min(max(x + dx, 0), G - 1);
                        s9 += fs[yy * G + xx];
                    }
                f = s9 * (1.0f / 9.0f);
                float c9 = 0.f;   // count: zero pad
                for (int dy = -1; dy <= 1; dy++)
                    for (int dx = -1; dx <= 1; dx++) {
                        int yy = y + dy, xx = x + dx;
                        if (yy >= 0 && yy < G && xx >= 0 && xx < G) c9 += cs[yy * G + xx];
                    }
                if (c9 > 0.f) c = 1.0f;
            }
            nf[k] = f; nc[k] = c;
        }
        __syncthreads();
        for (int k = 0; k < 16; k++) {
            int cell = tid + k * 1024;
            fs[cell] = nf[k];
            cs[cell] = nc[k];
        }
        __syncthreads();
    }
    for (int k = 0; k < 16; k++) {
        int cell = tid + k * 1024;
        fg[cell] = fs[cell];
    }
}

// ---------------- direct 128-pt DFT along rows, transposed output ------------
template <int PASS>
__global__ __launch_bounds__(256) void k_dft(const float* __restrict__ in,
                                             float* __restrict__ out,
                                             unsigned* __restrict__ famax) {
    __shared__ float2 xs[8][128];
    int blk = blockIdx.x;
    int rc = blk & 15;          // row-chunk: rows [rc*8, rc*8+8)
    int bf = blk >> 4;          // b*2 + f
    int tid = threadIdx.x;
    if (PASS == 0) {
        const float* re = in + ((size_t)(bf >> 1) * 4 + (size_t)(bf & 1) * 2) * GG + rc * 8 * G;
        const float* im = re + GG;
        for (int e = 0; e < 4; e++) {
            int idx = tid + e * 256;
            xs[idx >> 7][idx & 127] = make_float2(re[idx], im[idx]);
        }
    } else {
        const float2* cx = (const float2*)in + (size_t)bf * GG + rc * 8 * G;
        for (int e = 0; e < 4; e++) {
            int idx = tid + e * 256;
            xs[idx >> 7][idx & 127] = cx[idx];
        }
    }
    __syncthreads();

    int rloc = (tid >> 6) * 2;      // wave-uniform pair of rows
    int kk = tid & 63;              // k0 = kk, k1 = kk + 64
    float ang = -3.14159265358979323846f / 64.0f * (float)kk;
    float si, sr;
    sincosf(ang, &si, &sr);

    float e0r = 0.f, e0i = 0.f, o0r = 0.f, o0i = 0.f;
    float e1r = 0.f, e1i = 0.f, o1r = 0.f, o1i = 0.f;
    float tr = 1.f, ti = 0.f;
#pragma unroll 8
    for (int n = 0; n < 128; n += 2) {
        float2 x0 = xs[rloc][n];
        float2 x1 = xs[rloc + 1][n];
        e0r += x0.x * tr - x0.y * ti;  e0i += x0.x * ti + x0.y * tr;
        e1r += x1.x * tr - x1.y * ti;  e1i += x1.x * ti + x1.y * tr;
        float t2r = tr * sr - ti * si, t2i = tr * si + ti * sr;
        x0 = xs[rloc][n + 1];
        x1 = xs[rloc + 1][n + 1];
        o0r += x0.x * t2r - x0.y * t2i;  o0i += x0.x * t2i + x0.y * t2r;
        o1r += x1.x * t2r - x1.y * t2i;  o1i += x1.x * t2i + x1.y * t2r;
        tr = t2r * sr - t2i * si;  ti = t2r * si + t2i * sr;
    }

    float2 a00 = make_float2(e0r + o0r, e0i + o0i);
    float2 a01 = make_float2(e1r + o1r, e1i + o1i);
    float2 a10 = make_float2(e0r - o0r, e0i - o0i);
    float2 a11 = make_float2(e1r - o1r, e1i - o1i);

    float2* ob = (float2*)out + (size_t)bf * GG;
    int r0 = rc * 8 + rloc;
    ob[kk * G + r0]            = a00;
    ob[kk * G + r0 + 1]        = a01;
    ob[(kk + 64) * G + r0]     = a10;
    ob[(kk + 64) * G + r0 + 1] = a11;

    if (PASS == 1 && (bf & 1)) {   // fft_true: raw |Y| max per batch
        float m = fmaxf(fmaxf(sqrtf(a00.x * a00.x + a00.y * a00.y),
                              sqrtf(a01.x * a01.x + a01.y * a01.y)),
                        fmaxf(sqrtf(a10.x * a10.x + a10.y * a10.y),
                              sqrtf(a11.x * a11.x + a11.y * a11.y)));
        for (int off = 32; off; off >>= 1) m = fmaxf(m, __shfl_down(m, off));
        if ((tid & 63) == 0) atomicMax(&famax[bf >> 1], __float_as_uint(m));
    }
}

// ------------- loss: one block per batch, atomicAdd of per-batch mean -------
__global__ __launch_bounds__(1024) void k_loss(const float* __restrict__ Ybuf,
                                               const unsigned* __restrict__ famax,
                                               float* __restrict__ out) {
    int b = blockIdx.x;
    const float2* Yp = (const float2*)Ybuf + (size_t)(b * 2 + 0) * GG;
    const float2* Yt = (const float2*)Ybuf + (size_t)(b * 2 + 1) * GG;
    const float s = (4.5f / 127.0f) * (5.0f / 127.0f);   // dx*dy
    float fam = __uint_as_float(famax[b]) * s;
    float fam2 = fam * fam + 1e-10f;
    float thr = fam / 1000.0f;
    float swd = 0.f, smask = 0.f;
    for (int k = 0; k < 16; k++) {
        int idx = threadIdx.x + k * 1024;
        float2 p = Yp[idx], t = Yt[idx];
        float pr = p.x * s, pi = p.y * s;
        float qr = t.x * s, qi = t.y * s;
        float fa = sqrtf(qr * qr + qi * qi);
        if (fa >= thr) {
            float w = fa * fa / fam2;
            float dr = pr - qr, di = pi - qi;
            swd += (dr * dr + di * di) * w;
            smask += 1.f;
        }
    }
    for (int off = 32; off; off >>= 1) {
        swd += __shfl_down(swd, off);
        smask += __shfl_down(smask, off);
    }
    __shared__ float rs[16], rm[16];
    int wid = threadIdx.x >> 6, lane = threadIdx.x & 63;
    if (lane == 0) { rs[wid] = swd; rm[wid] = smask; }
    __syncthreads();
    if (threadIdx.x == 0) {
        float a = 0.f, m = 0.f;
        for (int w = 0; w < 16; w++) { a += rs[w]; m += rm[w]; }
        atomicAdd(out, (a / (m + 1e-10f)) * 0.125f);
    }
}

extern "C" void kernel_launch(void* const* d_in, const int* in_sizes, int n_in,
                              void* d_out, int out_size, void* d_ws, size_t ws_size,
                              hipStream_t stream) {
    const float* yp = (const float*)d_in[0];
    const float* yt = (const float*)d_in[1];
    const float* co = (const float*)d_in[2];
    float* ws = (float*)d_ws;
    float* field = ws + OFF_FIELD;
    float* cnt   = ws + OFF_COUNT;
    unsigned* famax = (unsigned*)(ws + OFF_FAMAX);
    unsigned* flags = (unsigned*)(ws + OFF_FLAG);
    float* T = ws + OFF_T;
    float* Y = ws + OFF_Y;
    unsigned* stage = (unsigned*)(ws + OFF_STAGE);

    int rep = 32;
    while (rep > 1 &&
           ((size_t)OFF_T + (size_t)BB * rep * SWORDS) * 4 > ws_size)
        rep >>= 1;

    if (rep == 32) {
        k_scatter_sort<<<BB * 32, 1024, SWORDS * sizeof(unsigned), stream>>>(
            (const float4*)co, (const float4*)yp, (const float4*)yt, stage, flags);
    } else {
        k_scatter<<<BB * rep, 1024, SWORDS * sizeof(unsigned), stream>>>(
            (const float4*)co, (const float4*)yp, (const float4*)yt, stage, flags, rep);
    }
    k_reduce<<<BB * (GG / 2) / 256, 256, 0, stream>>>(
        stage, field, cnt, famax, flags, (float*)d_out, rep);
    k_holefill<<<BB * 4, 1024, 2 * GG * sizeof(float), stream>>>(field, cnt, flags);
    k_dft<0><<<BB * 2 * 16, 256, 0, stream>>>(field, T, famax);
    k_dft<1><<<BB * 2 * 16, 256, 0, stream>>>(T, Y, famax);
    k_loss<<<BB, 1024, 0, stream>>>(Y, famax, (float*)d_out);
}

// Round 17
// 85.593 us; speedup vs baseline: 2.9360x; 1.0641x over previous
//
#include <hip/hip_runtime.h>
#include <hip/hip_fp16.h>
#include <math.h>

#define BB 8
#define NPTS 524288
#define G 128
#define GG (G*G)
#define SWORDS 40960      // u32 words per stage block: pv 16384 + tv 16384 + cn 8192

// ws layout in floats
#define OFF_FIELD 0
#define OFF_COUNT (BB*4*GG)              // 524288
#define OFF_FAMAX (OFF_COUNT + BB*GG)    // 655360 (8 u32 famax)
#define OFF_FLAG  (OFF_FAMAX + 8)        // 655368 (8 u32 per-batch hole flags)
#define OFF_T     (OFF_FAMAX + 24)       // 655384 (16B aligned)
#define OFF_Y     (OFF_T + BB*2*GG*2)
#define OFF_STAGE (OFF_T)                // stage aliases T/Y (dead before DFT)

__device__ __forceinline__ unsigned pack_h2(float x, float y) {
    __half2 h = __floats2half2_rn(x, y);
    return *(unsigned*)&h;
}

// ======== scatter via counting sort (R9/R16 body, measured 53us) ============
__global__ __launch_bounds__(1024) void k_scatter_sort(const float4* __restrict__ co4,
                                                       const float4* __restrict__ yp4,
                                                       const float4* __restrict__ yt4,
                                                       unsigned* __restrict__ stage,
                                                       unsigned* __restrict__ flags) {
    extern __shared__ unsigned sm[];                       // [40960]
    unsigned* cnt = sm;                                    // 8192 u32 = 16384 u16
    unsigned long long* data = (unsigned long long*)(sm + 8192);   // 16384 x 8B
    unsigned* dscr = sm + 8192;                            // scan scratch (data dead)

    const int t = threadIdx.x;
    const int blk = blockIdx.x;
    const unsigned qbase = (unsigned)blk * 4096u;

    if (blk == 0 && t < 8) flags[t] = 0u;                  // pre-zero hole flags

    for (int k = t; k < 8192; k += 1024) cnt[k] = 0u;
    __syncthreads();

    // ---- pass A: coords -> cell; atomic count gives rank (1 atomic/pt) ----
    unsigned cr[16];                                       // cell | rank<<16
#pragma unroll
    for (int g = 0; g < 4; g++) {
        unsigned qa = qbase + (unsigned)(g * 1024 + t);
        float4 A = co4[3u * qa], B = co4[3u * qa + 1], C = co4[3u * qa + 2];
        float cx[4], cy[4];
        cx[0] = A.x; cy[0] = A.y; cx[1] = A.w; cy[1] = B.x;
        cx[2] = B.z; cy[2] = B.w; cx[3] = C.y; cy[3] = C.z;
#pragma unroll
        for (int j = 0; j < 4; j++) {
            // exactly mirror reference arithmetic (div then mul)
            float xn = (cx[j] - 0.0f) / 4.5f * 127.0f;
            float yn = (cy[j] - 0.5f) / 5.0f * 127.0f;
            int xi = min(max((int)rintf(xn), 0), G - 1);
            int yi = min(max((int)rintf(yn), 0), G - 1);
            unsigned cell = (unsigned)(yi * G + xi);
            unsigned sh = (cell & 1u) * 16u;
            unsigned old = atomicAdd(&cnt[cell >> 1], 1u << sh);
            unsigned rank = (old >> sh) & 0xFFFFu;
            cr[g * 4 + j] = cell | (rank << 16);
        }
    }
    __syncthreads();

    // ---- exclusive prefix scan of 16384 u16 counts (in place -> offsets) ---
    unsigned w[8], ssum = 0;
#pragma unroll
    for (int j = 0; j < 8; j++) {
        w[j] = cnt[8 * t + j];
        ssum += (w[j] & 0xFFFFu) + (w[j] >> 16);
    }
    unsigned lane = (unsigned)t & 63u, wid = (unsigned)t >> 6;
    unsigned inc = ssum;
    for (int off = 1; off < 64; off <<= 1) {
        unsigned v = __shfl_up(inc, off);
        if (lane >= (unsigned)off) inc += v;
    }
    if (lane == 63u) dscr[wid] = inc;                      // 16 wave totals
    __syncthreads();
    unsigned wbase = 0;
#pragma unroll
    for (int k = 0; k < 16; k++) {
        unsigned v = dscr[k];
        if ((unsigned)k < wid) wbase += v;
    }
    unsigned ex = wbase + inc - ssum;                      // exclusive start
#pragma unroll
    for (int j = 0; j < 8; j++) {
        unsigned c0 = w[j] & 0xFFFFu, c1 = w[j] >> 16;
        cnt[8 * t + j] = ex | ((ex + c0) << 16);           // offsets (u16 pair)
        ex += c0 + c1;
    }
    __syncthreads();

    // ---- pass B: load values, place sorted (non-atomic ds_write_b64) ------
    const unsigned short* off16 = (const unsigned short*)cnt;
#pragma unroll
    for (int g = 0; g < 4; g++) {
        unsigned qa = qbase + (unsigned)(g * 1024 + t);
        float4 P0 = yp4[2u * qa], P1 = yp4[2u * qa + 1];
        float4 Q0 = yt4[2u * qa], Q1 = yt4[2u * qa + 1];
        unsigned pv[4], tv[4];
        pv[0] = pack_h2(P0.x, P0.y); pv[1] = pack_h2(P0.z, P0.w);
        pv[2] = pack_h2(P1.x, P1.y); pv[3] = pack_h2(P1.z, P1.w);
        tv[0] = pack_h2(Q0.x, Q0.y); tv[1] = pack_h2(Q0.z, Q0.w);
        tv[2] = pack_h2(Q1.x, Q1.y); tv[3] = pack_h2(Q1.z, Q1.w);
#pragma unroll
        for (int j = 0; j < 4; j++) {
            unsigned c = cr[g * 4 + j] & 0xFFFFu;
            unsigned rank = cr[g * 4 + j] >> 16;
            unsigned pos = (unsigned)off16[c] + rank;
            data[pos] = ((unsigned long long)tv[j] << 32) | (unsigned long long)pv[j];
        }
    }
    __syncthreads();

    // ---- pass C: per-cell f32 accumulation, pack f16, dump stage -----------
    unsigned* sb = stage + (size_t)blk * SWORDS;
    unsigned o[17];
#pragma unroll
    for (int j = 0; j < 8; j++) {
        unsigned wv = cnt[8 * t + j];
        o[2 * j] = wv & 0xFFFFu;
        o[2 * j + 1] = wv >> 16;
    }
    o[16] = (t == 1023) ? 16384u : (unsigned)off16[16 * (t + 1)];
    unsigned pvw[16], tvw[16];
#pragma unroll
    for (int k = 0; k < 16; k++) {
        float pr = 0.f, pi = 0.f, tr = 0.f, ti = 0.f;
        for (unsigned j = o[k]; j < o[k + 1]; j++) {
            unsigned long long d = data[j];
            unsigned lo = (unsigned)d, hi = (unsigned)(d >> 32);
            float2 fp = __half22float2(*(__half2*)&lo);
            float2 ft = __half22float2(*(__half2*)&hi);
            pr += fp.x; pi += fp.y; tr += ft.x; ti += ft.y;
        }
        pvw[k] = pack_h2(pr, pi);
        tvw[k] = pack_h2(tr, ti);
    }
#pragma unroll
    for (int j = 0; j < 4; j++)
        *(uint4*)(sb + 16 * t + 4 * j) = make_uint4(pvw[4*j], pvw[4*j+1], pvw[4*j+2], pvw[4*j+3]);
#pragma unroll
    for (int j = 0; j < 4; j++)
        *(uint4*)(sb + 16384 + 16 * t + 4 * j) = make_uint4(tvw[4*j], tvw[4*j+1], tvw[4*j+2], tvw[4*j+3]);
#pragma unroll
    for (int j = 0; j < 8; j++) {
        float ce = (float)(o[2 * j + 1] - o[2 * j]);
        float cd = (float)(o[2 * j + 2] - o[2 * j + 1]);
        sb[32768 + 8 * t + j] = pack_h2(ce, cd);
    }
}

// ======== direct scatter (fallback when ws can't hold rep=32 stage) =========
__global__ __launch_bounds__(1024) void k_scatter(const float4* __restrict__ co4,
                                                  const float4* __restrict__ yp4,
                                                  const float4* __restrict__ yt4,
                                                  unsigned* __restrict__ stage,
                                                  unsigned* __restrict__ flags,
                                                  int rep) {
    extern __shared__ unsigned sm[];   // [SWORDS]
    int blk = blockIdx.x;              // b*rep + r
    int r = blk % rep;
    int b = blk / rep;
    if (blk == 0 && threadIdx.x < 8) flags[threadIdx.x] = 0u;
    for (int k = threadIdx.x; k < SWORDS / 4; k += 1024)
        ((uint4*)sm)[k] = make_uint4(0u, 0u, 0u, 0u);
    __syncthreads();
    unsigned ldsbase = (unsigned)(uintptr_t)sm;
    int ppb = NPTS / rep;
    int nq = ppb >> 2;
    size_t qbase = ((size_t)b * NPTS + (size_t)r * ppb) >> 2;
#define DOPT(cx, cy, vx, vy, wx, wy) do {                                   \
        float xn = ((cx) - 0.0f) / 4.5f * 127.0f;                           \
        float yn = ((cy) - 0.5f) / 5.0f * 127.0f;                           \
        int xi = min(max((int)rintf(xn), 0), G - 1);                        \
        int yi = min(max((int)rintf(yn), 0), G - 1);                        \
        unsigned cell = (unsigned)(yi * G + xi);                            \
        unsigned av = ldsbase + cell * 4u;                                  \
        asm volatile("ds_pk_add_f16 %0, %1" :: "v"(av), "v"(pack_h2(vx, vy))); \
        asm volatile("ds_pk_add_f16 %0, %1" :: "v"(av + 65536u), "v"(pack_h2(wx, wy))); \
        unsigned ac = ldsbase + 131072u + (cell >> 1) * 4u;                 \
        unsigned cw = (cell & 1u) ? 0x3C000000u : 0x00003C00u;              \
        asm volatile("ds_pk_add_f16 %0, %1" :: "v"(ac), "v"(cw));           \
    } while (0)
    for (int q = threadIdx.x; q < nq; q += 2048) {
        size_t qa = qbase + q, qb = qa + 1024;
        float4 A0 = co4[3 * qa], B0 = co4[3 * qa + 1], C0 = co4[3 * qa + 2];
        float4 P00 = yp4[2 * qa], P01 = yp4[2 * qa + 1];
        float4 Q00 = yt4[2 * qa], Q01 = yt4[2 * qa + 1];
        float4 A1 = co4[3 * qb], B1 = co4[3 * qb + 1], C1 = co4[3 * qb + 2];
        float4 P10 = yp4[2 * qb], P11 = yp4[2 * qb + 1];
        float4 Q10 = yt4[2 * qb], Q11 = yt4[2 * qb + 1];
        DOPT(A0.x, A0.y, P00.x, P00.y, Q00.x, Q00.y);
        DOPT(A0.w, B0.x, P00.z, P00.w, Q00.z, Q00.w);
        DOPT(B0.z, B0.w, P01.x, P01.y, Q01.x, Q01.y);
        DOPT(C0.y, C0.z, P01.z, P01.w, Q01.z, Q01.w);
        DOPT(A1.x, A1.y, P10.x, P10.y, Q10.x, Q10.y);
        DOPT(A1.w, B1.x, P10.z, P10.w, Q10.z, Q10.w);
        DOPT(B1.z, B1.w, P11.x, P11.y, Q11.x, Q11.y);
        DOPT(C1.y, C1.z, P11.z, P11.w, Q11.z, Q11.w);
    }
#undef DOPT
    asm volatile("s_waitcnt lgkmcnt(0)" ::: "memory");
    __syncthreads();
    unsigned* sb = stage + (size_t)blk * SWORDS;
    for (int k = threadIdx.x * 4; k < SWORDS; k += 4096)
        *(uint4*)(sb + k) = *(const uint4*)(sm + k);
}

// ---- reduce replicas (f16->f32) + divide; zero famax/out; set hole flags ---
// REP>0: compile-time rep, fully unrollable (batched loads / MLP).
template <int REP>
__global__ __launch_bounds__(256) void k_reduce(const unsigned* __restrict__ stage,
                                                float* __restrict__ field,
                                                float* __restrict__ cnt,
                                                unsigned* __restrict__ famax,
                                                unsigned* __restrict__ flags,
                                                float* __restrict__ out,
                                                int rep_rt) {
    if (blockIdx.x == 0) {
        if (threadIdx.x < 8) famax[threadIdx.x] = 0u;
        if (threadIdx.x == 8) out[0] = 0.f;
    }
    int idx = blockIdx.x * 256 + threadIdx.x;    // b*8192 + k
    int k = idx & 8191;
    int b = idx >> 13;
    const int rep = (REP > 0) ? REP : rep_rt;
    const unsigned* sb = stage + (size_t)b * rep * SWORDS;
    float p0r = 0, p0i = 0, p1r = 0, p1i = 0;
    float t0r = 0, t0i = 0, t1r = 0, t1i = 0;
    float n0 = 0, n1 = 0;
#pragma unroll
    for (int r = 0; r < rep; r++) {
        const unsigned* pp = sb + (size_t)r * SWORDS;
        uint2 pv = *(const uint2*)(pp + 2 * k);
        uint2 tv = *(const uint2*)(pp + 16384 + 2 * k);
        unsigned cw = pp[32768 + k];
        float2 f;
        f = __half22float2(*(__half2*)&pv.x); p0r += f.x; p0i += f.y;
        f = __half22float2(*(__half2*)&pv.y); p1r += f.x; p1i += f.y;
        f = __half22float2(*(__half2*)&tv.x); t0r += f.x; t0i += f.y;
        f = __half22float2(*(__half2*)&tv.y); t1r += f.x; t1i += f.y;
        f = __half22float2(*(__half2*)&cw);   n0  += f.x; n1  += f.y;
    }
    int hole = (n0 == 0.f) || (n1 == 0.f);
    if (__any(hole)) {
        if ((threadIdx.x & 63) == 0) atomicOr(&flags[b], 1u);
    }
    if (n0 > 0.f) { p0r /= n0; p0i /= n0; t0r /= n0; t0i /= n0; }
    if (n1 > 0.f) { p1r /= n1; p1i /= n1; t1r /= n1; t1i /= n1; }
    float2* f2 = (float2*)field;
    size_t o = (size_t)b * 4 * (GG / 2) + k;
    f2[o]                = make_float2(p0r, p1r);
    f2[o + (GG / 2)]     = make_float2(p0i, p1i);
    f2[o + 2 * (GG / 2)] = make_float2(t0r, t1r);
    f2[o + 3 * (GG / 2)] = make_float2(t0i, t1i);
    ((float2*)cnt)[(size_t)b * (GG / 2) + k] = make_float2(n0, n1);
}

// ---------------- DFT pass 0 with integrated (flag-guarded) hole-fill -------
// Fast path (flags[b]==0, the statistical certainty at 32 pts/cell): identical
// to the old k_dft<0>. Rare path: race-free 14-row halo read + 3 shrinking-
// region fill iterations feeding the DFT directly (field is only read here).
__global__ __launch_bounds__(256) void k_dft0(const float* __restrict__ field,
                                              const float* __restrict__ cnt,
                                              const unsigned* __restrict__ flags,
                                              float* __restrict__ out) {
    __shared__ float2 xs[8][128];
    __shared__ float hre[14 * 128], him[14 * 128], hcn[14 * 128];
    int blk = blockIdx.x;
    int rc = blk & 15;          // row-chunk: rows [rc*8, rc*8+8)
    int bf = blk >> 4;          // b*2 + f
    int b = bf >> 1;
    int tid = threadIdx.x;
    const float* re = field + ((size_t)b * 4 + (size_t)(bf & 1) * 2) * GG;
    const float* im = re + GG;
    int r0 = rc * 8;

    if (flags[b] == 0u) {
        for (int e = 0; e < 4; e++) {
            int idx = tid + e * 256;
            xs[idx >> 7][idx & 127] = make_float2(re[r0 * G + idx], im[r0 * G + idx]);
        }
    } else {
        const float* cg = cnt + (size_t)b * GG;
        for (int k = 0; k < 7; k++) {          // load halo strip rows r0-3..r0+10
            int c = tid + k * 256;
            int s = c >> 7, x = c & 127;
            int gr = r0 - 3 + s;
            if (gr >= 0 && gr < G) {
                hre[c] = re[gr * G + x];
                him[c] = im[gr * G + x];
                hcn[c] = cg[gr * G + x];
            } else {
                hre[c] = 0.f; him[c] = 0.f; hcn[c] = 1.f;   // never read
            }
        }
        __syncthreads();
        for (int it = 0; it < 3; ++it) {
            float nr[7], ni[7], nc[7];
            int lo = r0 - 2 + it, hi = r0 + 9 - it;         // valid output rows
            for (int k = 0; k < 7; k++) {
                int c = tid + k * 256;
                int s = c >> 7, x = c & 127;
                int gr = r0 - 3 + s;
                float cv = hcn[c], fr = hre[c], fi = him[c];
                if (gr >= max(lo, 0) && gr <= min(hi, G - 1) && cv == 0.f) {
                    float sr = 0.f, si2 = 0.f, sc = 0.f;
                    for (int dy = -1; dy <= 1; dy++)
                        for (int dx = -1; dx <= 1; dx++) {
                            int yy = min(max(gr + dy, 0), G - 1);   // edge-replicate
                            int xx = min(max(x + dx, 0), G - 1);
                            int sidx = (yy - (r0 - 3)) * G + xx;
                            sr += hre[sidx];
                            si2 += him[sidx];
                            int ry = gr + dy, rx = x + dx;          // count: zero pad
                            if (ry >= 0 && ry < G && rx >= 0 && rx < G)
                                sc += hcn[(ry - (r0 - 3)) * G + rx];
                        }
                    fr = sr * (1.0f / 9.0f);
                    fi = si2 * (1.0f / 9.0f);
                    if (sc > 0.f) cv = 1.0f;
                }
                nr[k] = fr; ni[k] = fi; nc[k] = cv;
            }
            __syncthreads();
            for (int k = 0; k < 7; k++) {
                int c = tid + k * 256;
                hre[c] = nr[k]; him[c] = ni[k]; hcn[c] = nc[k];
            }
            __syncthreads();
        }
        for (int e = 0; e < 4; e++) {
            int idx = tid + e * 256;
            int row = idx >> 7, x = idx & 127;
            int c = (row + 3) * G + x;
            xs[row][x] = make_float2(hre[c], him[c]);
        }
    }
    __syncthreads();

    int rloc = (tid >> 6) * 2;      // wave-uniform pair of rows
    int kk = tid & 63;              // k0 = kk, k1 = kk + 64
    float ang = -3.14159265358979323846f / 64.0f * (float)kk;
    float si, sr;
    sincosf(ang, &si, &sr);

    float e0r = 0.f, e0i = 0.f, o0r = 0.f, o0i = 0.f;
    float e1r = 0.f, e1i = 0.f, o1r = 0.f, o1i = 0.f;
    float tr = 1.f, ti = 0.f;
#pragma unroll 8
    for (int n = 0; n < 128; n += 2) {
        float2 x0 = xs[rloc][n];
        float2 x1 = xs[rloc + 1][n];
        e0r += x0.x * tr - x0.y * ti;  e0i += x0.x * ti + x0.y * tr;
        e1r += x1.x * tr - x1.y * ti;  e1i += x1.x * ti + x1.y * tr;
        float t2r = tr * sr - ti * si, t2i = tr * si + ti * sr;
        x0 = xs[rloc][n + 1];
        x1 = xs[rloc + 1][n + 1];
        o0r += x0.x * t2r - x0.y * t2i;  o0i += x0.x * t2i + x0.y * t2r;
        o1r += x1.x * t2r - x1.y * t2i;  o1i += x1.x * t2i + x1.y * t2r;
        tr = t2r * sr - t2i * si;  ti = t2r * si + t2i * sr;
    }

    float2* ob = (float2*)out + (size_t)bf * GG;
    int orow = r0 + rloc;
    ob[kk * G + orow]            = make_float2(e0r + o0r, e0i + o0i);
    ob[kk * G + orow + 1]        = make_float2(e1r + o1r, e1i + o1i);
    ob[(kk + 64) * G + orow]     = make_float2(e0r - o0r, e0i - o0i);
    ob[(kk + 64) * G + orow + 1] = make_float2(e1r - o1r, e1i - o1i);
}

// ---------------- DFT pass 1 (T -> Y) + famax over fft_true -----------------
__global__ __launch_bounds__(256) void k_dft1(const float* __restrict__ in,
                                              float* __restrict__ out,
                                              unsigned* __restrict__ famax) {
    __shared__ float2 xs[8][128];
    int blk = blockIdx.x;
    int rc = blk & 15;
    int bf = blk >> 4;
    int tid = threadIdx.x;
    const float2* cx = (const float2*)in + (size_t)bf * GG + rc * 8 * G;
    for (int e = 0; e < 4; e++) {
        int idx = tid + e * 256;
        xs[idx >> 7][idx & 127] = cx[idx];
    }
    __syncthreads();

    int rloc = (tid >> 6) * 2;
    int kk = tid & 63;
    float ang = -3.14159265358979323846f / 64.0f * (float)kk;
    float si, sr;
    sincosf(ang, &si, &sr);

    float e0r = 0.f, e0i = 0.f, o0r = 0.f, o0i = 0.f;
    float e1r = 0.f, e1i = 0.f, o1r = 0.f, o1i = 0.f;
    float tr = 1.f, ti = 0.f;
#pragma unroll 8
    for (int n = 0; n < 128; n += 2) {
        float2 x0 = xs[rloc][n];
        float2 x1 = xs[rloc + 1][n];
        e0r += x0.x * tr - x0.y * ti;  e0i += x0.x * ti + x0.y * tr;
        e1r += x1.x * tr - x1.y * ti;  e1i += x1.x * ti + x1.y * tr;
        float t2r = tr * sr - ti * si, t2i = tr * si + ti * sr;
        x0 = xs[rloc][n + 1];
        x1 = xs[rloc + 1][n + 1];
        o0r += x0.x * t2r - x0.y * t2i;  o0i += x0.x * t2i + x0.y * t2r;
        o1r += x1.x * t2r - x1.y * t2i;  o1i += x1.x * t2i + x1.y * t2r;
        tr = t2r * sr - t2i * si;  ti = t2r * si + t2i * sr;
    }

    float2 a00 = make_float2(e0r + o0r, e0i + o0i);
    float2 a01 = make_float2(e1r + o1r, e1i + o1i);
    float2 a10 = make_float2(e0r - o0r, e0i - o0i);
    float2 a11 = make_float2(e1r - o1r, e1i - o1i);

    float2* ob = (float2*)out + (size_t)bf * GG;
    int r0 = rc * 8 + rloc;
    ob[kk * G + r0]            = a00;
    ob[kk * G + r0 + 1]        = a01;
    ob[(kk + 64) * G + r0]     = a10;
    ob[(kk + 64) * G + r0 + 1] = a11;

    if (bf & 1) {   // fft_true: raw |Y| max per batch
        float m = fmaxf(fmaxf(sqrtf(a00.x * a00.x + a00.y * a00.y),
                              sqrtf(a01.x * a01.x + a01.y * a01.y)),
                        fmaxf(sqrtf(a10.x * a10.x + a10.y * a10.y),
                              sqrtf(a11.x * a11.x + a11.y * a11.y)));
        for (int off = 32; off; off >>= 1) m = fmaxf(m, __shfl_down(m, off));
        if ((tid & 63) == 0) atomicMax(&famax[bf >> 1], __float_as_uint(m));
    }
}

// ------------- loss: one block per batch, atomicAdd of per-batch mean -------
__global__ __launch_bounds__(1024) void k_loss(const float* __restrict__ Ybuf,
                                               const unsigned* __restrict__ famax,
                                               float* __restrict__ out) {
    int b = blockIdx.x;
    const float2* Yp = (const float2*)Ybuf + (size_t)(b * 2 + 0) * GG;
    const float2* Yt = (const float2*)Ybuf + (size_t)(b * 2 + 1) * GG;
    const float s = (4.5f / 127.0f) * (5.0f / 127.0f);   // dx*dy
    float fam = __uint_as_float(famax[b]) * s;
    float fam2 = fam * fam + 1e-10f;
    float thr = fam / 1000.0f;
    float swd = 0.f, smask = 0.f;
    for (int k = 0; k < 16; k++) {
        int idx = threadIdx.x + k * 1024;
        float2 p = Yp[idx], t = Yt[idx];
        float pr = p.x * s, pi = p.y * s;
        float qr = t.x * s, qi = t.y * s;
        float fa = sqrtf(qr * qr + qi * qi);
        if (fa >= thr) {
            float w = fa * fa / fam2;
            float dr = pr - qr, di = pi - qi;
            swd += (dr * dr + di * di) * w;
            smask += 1.f;
        }
    }
    for (int off = 32; off; off >>= 1) {
        swd += __shfl_down(swd, off);
        smask += __shfl_down(smask, off);
    }
    __shared__ float rs[16], rm[16];
    int wid = threadIdx.x >> 6, lane = threadIdx.x & 63;
    if (lane == 0) { rs[wid] = swd; rm[wid] = smask; }
    __syncthreads();
    if (threadIdx.x == 0) {
        float a = 0.f, m = 0.f;
        for (int w = 0; w < 16; w++) { a += rs[w]; m += rm[w]; }
        atomicAdd(out, (a / (m + 1e-10f)) * 0.125f);
    }
}

extern "C" void kernel_launch(void* const* d_in, const int* in_sizes, int n_in,
                              void* d_out, int out_size, void* d_ws, size_t ws_size,
                              hipStream_t stream) {
    const float* yp = (const float*)d_in[0];
    const float* yt = (const float*)d_in[1];
    const float* co = (const float*)d_in[2];
    float* ws = (float*)d_ws;
    float* field = ws + OFF_FIELD;
    float* cnt   = ws + OFF_COUNT;
    unsigned* famax = (unsigned*)(ws + OFF_FAMAX);
    unsigned* flags = (unsigned*)(ws + OFF_FLAG);
    float* T = ws + OFF_T;
    float* Y = ws + OFF_Y;
    unsigned* stage = (unsigned*)(ws + OFF_STAGE);

    int rep = 32;
    while (rep > 1 &&
           ((size_t)OFF_T + (size_t)BB * rep * SWORDS) * 4 > ws_size)
        rep >>= 1;

    if (rep == 32) {
        k_scatter_sort<<<BB * 32, 1024, SWORDS * sizeof(unsigned), stream>>>(
            (const float4*)co, (const float4*)yp, (const float4*)yt, stage, flags);
        k_reduce<32><<<BB * (GG / 2) / 256, 256, 0, stream>>>(
            stage, field, cnt, famax, flags, (float*)d_out, 32);
    } else {
        k_scatter<<<BB * rep, 1024, SWORDS * sizeof(unsigned), stream>>>(
            (const float4*)co, (const float4*)yp, (const float4*)yt, stage, flags, rep);
        k_reduce<0><<<BB * (GG / 2) / 256, 256, 0, stream>>>(
            stage, field, cnt, famax, flags, (float*)d_out, rep);
    }
    k_dft0<<<BB * 2 * 16, 256, 0, stream>>>(field, cnt, flags, T);
    k_dft1<<<BB * 2 * 16, 256, 0, stream>>>(T, Y, famax);
    k_loss<<<BB, 1024, 0, stream>>>(Y, famax, (float*)d_out);
}